// Round 1
// baseline (572.444 us; speedup 1.0000x reference)
//
#include <hip/hip_runtime.h>

// GCN encoder: 2x GCNConv (PyG semantics: add self-loops, symmetric norm, aggregate at col)
// x:[100000,256] f32, W1:[256,128], b1:[128], W2:[128,128], b2:[128], edge_index:[2,1600000] int
// out:[100000,128] f32

#define NN 100000
#define NH 128

// ---------------- CSR build ----------------
__global__ void k_count(const int* __restrict__ col, int* __restrict__ cnt, int E) {
    int e = blockIdx.x * 256 + threadIdx.x;
    if (e < E) atomicAdd(&cnt[col[e]], 1);
}

__global__ void k_dinv(const int* __restrict__ cnt, float* __restrict__ dinv, int n) {
    int i = blockIdx.x * 256 + threadIdx.x;
    if (i < n) dinv[i] = rsqrtf(1.0f + (float)cnt[i]);   // deg = 1 (self-loop) + in-degree
}

__global__ void k_scan_block(const int* __restrict__ in, int* __restrict__ out,
                             int* __restrict__ bsum, int n) {
    __shared__ int s[256];
    int i = blockIdx.x * 256 + threadIdx.x;
    int v = (i < n) ? in[i] : 0;
    s[threadIdx.x] = v;
    __syncthreads();
    for (int off = 1; off < 256; off <<= 1) {
        int t = (threadIdx.x >= off) ? s[threadIdx.x - off] : 0;
        __syncthreads();
        s[threadIdx.x] += t;
        __syncthreads();
    }
    if (i < n) out[i] = s[threadIdx.x] - v;             // exclusive within block
    if (threadIdx.x == 255) bsum[blockIdx.x] = s[255];  // block total
}

__global__ void k_scan_sums(int* bsum, int nb) {  // nb <= 512, single block of 512
    __shared__ int s[512];
    int tid = threadIdx.x;
    int v = (tid < nb) ? bsum[tid] : 0;
    s[tid] = v;
    __syncthreads();
    for (int off = 1; off < 512; off <<= 1) {
        int t = (tid >= off) ? s[tid - off] : 0;
        __syncthreads();
        s[tid] += t;
        __syncthreads();
    }
    if (tid < nb) bsum[tid] = s[tid] - v;               // exclusive block offsets
}

__global__ void k_scan_add(int* __restrict__ off, const int* __restrict__ bsum,
                           const int* __restrict__ cnt, int n) {
    int i = blockIdx.x * 256 + threadIdx.x;
    if (i < n) {
        int o = off[i] + bsum[blockIdx.x];
        off[i] = o;
        if (i == n - 1) off[n] = o + cnt[i];
    }
}

__global__ void k_fill(const int* __restrict__ row, const int* __restrict__ col,
                       const int* __restrict__ off, int* __restrict__ cur,
                       int* __restrict__ src, int E) {
    int e = blockIdx.x * 256 + threadIdx.x;
    if (e < E) {
        int c = col[e];
        int slot = off[c] + atomicAdd(&cur[c], 1);
        src[slot] = row[e];
    }
}

// ---------------- f32 GEMM: C[M,128] = A[M,K] @ W[K,128] ----------------
template <int K>
__global__ __launch_bounds__(256) void k_gemm(const float* __restrict__ A,
                                              const float* __restrict__ W,
                                              float* __restrict__ C, int M) {
    __shared__ float sA[64][33];     // +1 pad
    __shared__ float sW[32][128];
    int tid = threadIdx.x;
    int rowBase = blockIdx.x * 64;
    int tr = tid >> 5;   // 0..7  (8 row-groups of 8 rows)
    int tc = tid & 31;   // 0..31 (4 cols each)

    float4 acc[8];
#pragma unroll
    for (int i = 0; i < 8; ++i) acc[i] = make_float4(0.f, 0.f, 0.f, 0.f);

    for (int k0 = 0; k0 < K; k0 += 32) {
        // stage A: 64 rows x 32 k
        {
            int r  = tid >> 3;   // 0..31
            int cg = tid & 7;    // float4 group
#pragma unroll
            for (int p = 0; p < 2; ++p) {
                int rr = r + p * 32;
                int gr = rowBase + rr;
                if (gr >= M) gr = M - 1;
                float4 av = *(const float4*)&A[(long)gr * K + k0 + cg * 4];
                sA[rr][cg * 4 + 0] = av.x;
                sA[rr][cg * 4 + 1] = av.y;
                sA[rr][cg * 4 + 2] = av.z;
                sA[rr][cg * 4 + 3] = av.w;
            }
        }
        // stage W: 32 k x 128 cols
#pragma unroll
        for (int p = 0; p < 4; ++p) {
            int kr = (tid >> 5) + p * 8;
            float4 wv = *(const float4*)&W[(long)(k0 + kr) * 128 + tc * 4];
            *(float4*)&sW[kr][tc * 4] = wv;
        }
        __syncthreads();
#pragma unroll
        for (int kk = 0; kk < 32; ++kk) {
            float4 wv = *(const float4*)&sW[kk][tc * 4];
#pragma unroll
            for (int i = 0; i < 8; ++i) {
                float a = sA[tr * 8 + i][kk];
                acc[i].x += a * wv.x;
                acc[i].y += a * wv.y;
                acc[i].z += a * wv.z;
                acc[i].w += a * wv.w;
            }
        }
        __syncthreads();
    }
#pragma unroll
    for (int i = 0; i < 8; ++i) {
        int r = rowBase + tr * 8 + i;
        if (r < M) *(float4*)&C[(long)r * 128 + tc * 4] = acc[i];
    }
}

// ---------------- aggregate: out[i] = sum_{e: col=i} h[row_e]*dinv[row]*dinv[i] + h[i]*dinv[i]^2 + b ----------------
template <bool RELU>
__global__ __launch_bounds__(256) void k_agg(const float* __restrict__ h,
                                             const float* __restrict__ dinv,
                                             const int* __restrict__ off,
                                             const int* __restrict__ src,
                                             const float* __restrict__ bias,
                                             float* __restrict__ out, int n) {
    int gid  = blockIdx.x * 256 + threadIdx.x;
    int node = gid >> 5;
    int lane = gid & 31;
    if (node >= n) return;
    float di = dinv[node];
    float4 hv = *(const float4*)&h[(long)node * NH + lane * 4];
    float w0 = di * di;
    float4 acc = make_float4(hv.x * w0, hv.y * w0, hv.z * w0, hv.w * w0);
    int e1 = off[node + 1];
    for (int e = off[node]; e < e1; ++e) {
        int s = src[e];
        float w = dinv[s] * di;
        float4 v = *(const float4*)&h[(long)s * NH + lane * 4];
        acc.x += v.x * w;
        acc.y += v.y * w;
        acc.z += v.z * w;
        acc.w += v.w * w;
    }
    float4 b = *(const float4*)&bias[lane * 4];
    acc.x += b.x; acc.y += b.y; acc.z += b.z; acc.w += b.w;
    if (RELU) {
        acc.x = fmaxf(acc.x, 0.f); acc.y = fmaxf(acc.y, 0.f);
        acc.z = fmaxf(acc.z, 0.f); acc.w = fmaxf(acc.w, 0.f);
    }
    *(float4*)&out[(long)node * NH + lane * 4] = acc;
}

extern "C" void kernel_launch(void* const* d_in, const int* in_sizes, int n_in,
                              void* d_out, int out_size, void* d_ws, size_t ws_size,
                              hipStream_t stream) {
    const float* x  = (const float*)d_in[0];
    const float* W1 = (const float*)d_in[1];
    const float* b1 = (const float*)d_in[2];
    const float* W2 = (const float*)d_in[3];
    const float* b2 = (const float*)d_in[4];
    const int*   ei = (const int*)d_in[5];

    const int n = NN;
    const int E = in_sizes[5] / 2;
    const int* row = ei;        // sources
    const int* col = ei + E;    // targets

    char* ws = (char*)d_ws;
    size_t o = 0;
    auto alloc = [&](size_t bytes) {
        void* p = ws + o;
        o = (o + bytes + 255) & ~(size_t)255;
        return p;
    };
    int*   cnt  = (int*)alloc((size_t)n * 4);
    int*   offs = (int*)alloc((size_t)(n + 1) * 4);
    int*   bsum = (int*)alloc(512 * 4);
    float* dinv = (float*)alloc((size_t)n * 4);
    int*   csrc = (int*)alloc((size_t)E * 4);
    float* bufH = (float*)alloc((size_t)n * NH * 4);
    float* bufG = (float*)alloc((size_t)n * NH * 4);

    int nb = (n + 255) / 256;  // 391

    hipMemsetAsync(cnt, 0, (size_t)n * 4, stream);
    k_count<<<(E + 255) / 256, 256, 0, stream>>>(col, cnt, E);
    k_dinv<<<nb, 256, 0, stream>>>(cnt, dinv, n);
    k_scan_block<<<nb, 256, 0, stream>>>(cnt, offs, bsum, n);
    k_scan_sums<<<1, 512, 0, stream>>>(bsum, nb);
    k_scan_add<<<nb, 256, 0, stream>>>(offs, bsum, cnt, n);
    hipMemsetAsync(cnt, 0, (size_t)n * 4, stream);  // reuse as cursor
    k_fill<<<(E + 255) / 256, 256, 0, stream>>>(row, col, offs, cnt, csrc, E);

    // layer 1: h = x@W1 ; g = relu(agg(h) + b1)
    k_gemm<256><<<(n + 63) / 64, 256, 0, stream>>>(x, W1, bufH, n);
    k_agg<true><<<(n * 32 + 255) / 256, 256, 0, stream>>>(bufH, dinv, offs, csrc, b1, bufG, n);
    // layer 2: h = g@W2 ; out = agg(h) + b2
    k_gemm<128><<<(n + 63) / 64, 256, 0, stream>>>(bufG, W2, bufH, n);
    k_agg<false><<<(n * 32 + 255) / 256, 256, 0, stream>>>(bufH, dinv, offs, csrc, b2, (float*)d_out, n);
}